// Round 1
// baseline (273.980 us; speedup 1.0000x reference)
//
#include <hip/hip_runtime.h>
#include <hip/hip_bf16.h>

#define B_ 2
#define S_ 8192
#define DIM_ 1024
#define NH_ 16
#define NKV_ 4
#define HD_ 64
#define NC_ 64

typedef __bf16 bf16x8 __attribute__((ext_vector_type(8)));
typedef float f32x4 __attribute__((ext_vector_type(4)));
using bf16 = __hip_bfloat16;

// async global->LDS, 16B per lane; LDS dst = base + lane*16 (wave-uniform base)
#define ASYNC16(gp, lp) __builtin_amdgcn_global_load_lds( \
    (__attribute__((address_space(1))) void*)(void*)(gp), \
    (__attribute__((address_space(3))) void*)(void*)(lp), 16, 0, 0)

// ---------------- fused prep: x->bf16, weights->bf16, rope tables ----------------
__global__ __launch_bounds__(256) void prep_kernel(const float* __restrict__ x, const float* __restrict__ Wq,
                                                   const float* __restrict__ Wk, const float* __restrict__ Wv,
                                                   const float* __restrict__ Wo, bf16* __restrict__ xb,
                                                   bf16* __restrict__ wqkv, bf16* __restrict__ wo,
                                                   float* __restrict__ cosd, float* __restrict__ sind) {
    int bid = blockIdx.x;
    if (bid < 16384) {  // x convert: 16,777,216 elems
        size_t i = ((size_t)bid * 256 + threadIdx.x) * 4;
        const float4 f = *(const float4*)(x + i);
        bf16 t[4];
        t[0] = __float2bfloat16(f.x); t[1] = __float2bfloat16(f.y);
        t[2] = __float2bfloat16(f.z); t[3] = __float2bfloat16(f.w);
        *(uint2*)(xb + i) = *(const uint2*)t;
    } else if (bid < 18944) {  // weights: Wq|Wk|Wv -> wqkv, Wo -> wo
        size_t e = ((size_t)(bid - 16384) * 256 + threadIdx.x) * 4;
        const float* src;
        bf16* dst;
        if (e < 1048576)        { src = Wq + e;             dst = wqkv + e; }
        else if (e < 1310720)   { src = Wk + (e - 1048576); dst = wqkv + e; }
        else if (e < 1572864)   { src = Wv + (e - 1310720); dst = wqkv + e; }
        else                    { src = Wo + (e - 1572864); dst = wo + (e - 1572864); }
        const float4 f = *(const float4*)src;
        bf16 t[4];
        t[0] = __float2bfloat16(f.x); t[1] = __float2bfloat16(f.y);
        t[2] = __float2bfloat16(f.z); t[3] = __float2bfloat16(f.w);
        *(uint2*)dst = *(const uint2*)t;
    } else {  // rope tables: S_*32 entries, f64 range-reduction + hw sin/cos
        int idx = (bid - 18944) * 256 + threadIdx.x;
        int s = idx >> 5, i = idx & 31;
        double inv = exp((double)i * (-9.210340371976184 / 32.0));  // 10000^(-i/32)
        double rev = ((double)s * inv) * 0.15915494309189535;       // angle / 2pi
        double frac = rev - floor(rev);
        float a = (float)frac * 6.2831853071795865f;
        cosd[idx] = __cosf(a);
        sind[idx] = __sinf(a);
    }
}

// ---------------- 256x256-tile 8-phase GEMM: C[M][N] = A[M][1024] * B[N][1024]^T ----------------
// T3+T4+T5 port of the 8-phase template: 512 thr = 8 waves (2M x 4N), per-wave C = 128x64
// (8x4 16x16x32 frags). K hardcoded = 1024 (both gemms). LDS 128 KiB: As/Bs[2 bufs][256][64]
// bf16, XOR chunk-swizzle via pre-swizzled GLOBAL source (LDS stays linear for global_load_lds;
// same involution on the read side -> 0 bank conflicts, proven by current kernel's counters).
//
// Schedule per iteration = 2 K-tiles (even tile in buf0, odd in buf1), 8 phases, each phase:
//   [ds_read reg subtile][stage one half-tile (2x gload_lds)][s_barrier][setprio1; 16 MFMA;
//   setprio0][s_barrier].
// Stage slot = first phase where target region is dead:
//   P1 stg b1.A.lo(t1) | P2 stg b1.A.hi(t1) | P3 stg b0.B.lo(t0+2) | P4 stg b0.A.lo + vmcnt(4)
//   P5 stg b0.A.hi | P6 stg b0.B.hi | P7 stg b1.B.lo(t1+2) | P8 stg b1.B.hi + vmcnt(4)
// vmcnt(4) = 2 half-tiles allowed in flight across the wait; NEVER drained to 0 in steady
// state (the m97 ceiling was exactly that drain). Last iteration peeled: stages for tiles >=16
// skipped, P4 waits vmcnt(0) so tile15's A (staged P1/P2) is resident.
template <typename OT>
__global__ __launch_bounds__(512, 1) void gemm256_kernel(const bf16* __restrict__ A, const bf16* __restrict__ Bm,
                                                         OT* __restrict__ C, int N, int rope_ncols,
                                                         const float* __restrict__ cosd,
                                                         const float* __restrict__ sind) {
    __shared__ bf16 As[2][16384];   // [buf][256 rows][64 cols]
    __shared__ bf16 Bs[2][16384];
    const int tid = threadIdx.x;
    const int wave = tid >> 6, lane = tid & 63;
    const int wr = wave >> 2, wc = wave & 3;
    const int wm = wr * 128, wn = wc * 64;
    const int lr = lane & 15, quad = lane >> 4;
    const int bm = blockIdx.x * 256, bn = blockIdx.y * 256;
    // staging geometry: each wave covers 16 rows per half-tile via 2 loads (8 rows each);
    // global source column pre-swizzled so linear LDS ends up chunk-XOR'd by (row&7).
    const int sub0 = wave * 2, sub1 = sub0 + 1;
    const int rr = lane >> 3;                 // row within 8-row group
    const int cc = ((lane & 7) ^ rr) * 8;     // swizzled source chunk (elems)
    const bf16* Ab = A + (size_t)(bm + rr) * 1024 + cc;
    const bf16* Bb = Bm + (size_t)(bn + rr) * 1024 + cc;

#define STG(dst, base, half, k0)                                                                        \
    do {                                                                                                \
        ASYNC16((base) + (size_t)((half) * 128 + sub0 * 8) * 1024 + (k0), &(dst)[(half) * 8192 + sub0 * 512]); \
        ASYNC16((base) + (size_t)((half) * 128 + sub1 * 8) * 1024 + (k0), &(dst)[(half) * 8192 + sub1 * 512]); \
    } while (0)

#define RD_A(c, mbase)                                                                                  \
    do {                                                                                                \
        _Pragma("unroll") for (int mi_ = 0; mi_ < 4; ++mi_)                                             \
            _Pragma("unroll") for (int kx_ = 0; kx_ < 2; ++kx_)                                         \
                af[mi_][kx_] = *(const bf16x8*)&As[c][(wm + (mbase) + mi_ * 16 + lr) * 64 +              \
                                                     ((kx_ * 4 + quad) ^ (lr & 7)) * 8];                \
    } while (0)

#define RD_B2(c, n0)                                                                                    \
    do {                                                                                                \
        _Pragma("unroll") for (int ni_ = 0; ni_ < 2; ++ni_)                                             \
            _Pragma("unroll") for (int kx_ = 0; kx_ < 2; ++kx_)                                         \
                bfr[(n0) + ni_][kx_] = *(const bf16x8*)&Bs[c][(wn + ((n0) + ni_) * 16 + lr) * 64 +      \
                                                              ((kx_ * 4 + quad) ^ (lr & 7)) * 8];       \
    } while (0)

#define MM(mo, n0)                                                                                      \
    do {                                                                                                \
        __builtin_amdgcn_s_setprio(1);                                                                  \
        _Pragma("unroll") for (int kx_ = 0; kx_ < 2; ++kx_)                                             \
            _Pragma("unroll") for (int mi_ = 0; mi_ < 4; ++mi_)                                         \
                _Pragma("unroll") for (int ni_ = 0; ni_ < 2; ++ni_)                                     \
                    acc[(mo) + mi_][(n0) + ni_] = __builtin_amdgcn_mfma_f32_16x16x32_bf16(              \
                        af[mi_][kx_], bfr[(n0) + ni_][kx_], acc[(mo) + mi_][(n0) + ni_], 0, 0, 0);      \
        __builtin_amdgcn_s_setprio(0);                                                                  \
    } while (0)

#define BAR()                                                                                           \
    do {                                                                                                \
        __builtin_amdgcn_s_barrier();                                                                   \
        __builtin_amdgcn_sched_barrier(0);                                                              \
    } while (0)

#define GQ_ITER(K1, K2, K3, LAST)                                                                       \
    do {                                                                                                \
        /* P1 */ RD_A(0, 0); RD_B2(0, 0); STG(As[1], Ab, 0, (K1)); BAR(); MM(0, 0); BAR();              \
        /* P2 */ RD_B2(0, 2); STG(As[1], Ab, 1, (K1)); BAR(); MM(0, 2); BAR();                          \
        /* P3 */ RD_A(0, 64); if (!(LAST)) { STG(Bs[0], Bb, 0, (K2)); } BAR(); MM(4, 0); BAR();         \
        /* P4 */ if (!(LAST)) { STG(As[0], Ab, 0, (K2)); asm volatile("s_waitcnt vmcnt(4)"); }          \
                 else { asm volatile("s_waitcnt vmcnt(0)"); }                                           \
                 __builtin_amdgcn_sched_barrier(0); BAR(); MM(4, 2); BAR();                             \
        /* P5 */ RD_A(1, 0); RD_B2(1, 0); if (!(LAST)) { STG(As[0], Ab, 1, (K2)); } BAR(); MM(0, 0); BAR(); \
        /* P6 */ RD_B2(1, 2); if (!(LAST)) { STG(Bs[0], Bb, 1, (K2)); } BAR(); MM(0, 2); BAR();         \
        /* P7 */ RD_A(1, 64); if (!(LAST)) { STG(Bs[1], Bb, 0, (K3)); } BAR(); MM(4, 0); BAR();         \
        /* P8 */ if (!(LAST)) { STG(Bs[1], Bb, 1, (K3)); asm volatile("s_waitcnt vmcnt(4)");            \
                                __builtin_amdgcn_sched_barrier(0); }                                    \
                 BAR(); MM(4, 2); BAR();                                                                \
    } while (0)

    f32x4 acc[8][4] = {};
    bf16x8 af[4][2];    // current A m-frag half (m0-3 or m4-7) x kk
    bf16x8 bfr[4][2];   // B n-frags 0..3 x kk

    // prologue: tile0 -> buf0 (order B.lo, A.lo, A.hi, B.hi), tile1 B halves -> buf1.
    // vmcnt(4): tile0's 8 loads landed, tile1's B (last 4) may stay in flight.
    STG(Bs[0], Bb, 0, 0); STG(As[0], Ab, 0, 0); STG(As[0], Ab, 1, 0); STG(Bs[0], Bb, 1, 0);
    STG(Bs[1], Bb, 0, 64); STG(Bs[1], Bb, 1, 64);
    asm volatile("s_waitcnt vmcnt(4)");
    __builtin_amdgcn_sched_barrier(0);
    __builtin_amdgcn_s_barrier();

    for (int i = 0; i < 7; ++i) {
        GQ_ITER(i * 128 + 64, i * 128 + 128, i * 128 + 192, 0);
    }
    GQ_ITER(960, 0, 0, 1);

    if (bn + wn < rope_ncols) {
        // wave's 64 columns = exactly one head; pair (i, i+32) = (acc[mi][ni], acc[mi][ni+2])
#pragma unroll
        for (int mi = 0; mi < 8; ++mi)
#pragma unroll
            for (int r = 0; r < 4; ++r) {
                int row = bm + wm + mi * 16 + quad * 4 + r;
                int s = row & (S_ - 1);
#pragma unroll
                for (int ni = 0; ni < 2; ++ni) {
                    int ii = ni * 16 + lr;
                    float cs = cosd[(s << 5) + ii];
                    float sn = sind[(s << 5) + ii];
                    float x1 = acc[mi][ni][r], x2 = acc[mi][ni + 2][r];
                    acc[mi][ni][r] = x1 * cs - x2 * sn;
                    acc[mi][ni + 2][r] = x2 * cs + x1 * sn;
                }
            }
    }
#pragma unroll
    for (int mi = 0; mi < 8; ++mi)
#pragma unroll
        for (int ni = 0; ni < 4; ++ni)
#pragma unroll
            for (int r = 0; r < 4; ++r) {
                int row = bm + wm + mi * 16 + quad * 4 + r;
                int col = bn + wn + ni * 16 + lr;
                float v = acc[mi][ni][r];
                if constexpr (__is_same(OT, float)) C[(size_t)row * N + col] = v;
                else C[(size_t)row * N + col] = __float2bfloat16(v);
            }
#undef STG
#undef RD_A
#undef RD_B2
#undef MM
#undef BAR
#undef GQ_ITER
}

// XOR chunk swizzle for transposed LDS tiles (row stride 136 elems, b128-aligned):
// element (row e, col t): addr = e*136 + ((chunk & ~7)<<3) + (((chunk ^ (e>>3)) & 7)<<3) + (t&7),
// chunk = t>>3. Bit 3 of chunk MUST be kept (cols 0..127 -> chunk 0..15); dropping it
// aliases t and t+64 (the R4 NaN bug). Transpose stores hit 8 distinct banks; b128 reads aligned.

// ---------------- per-chunk KV contribution: CT[e][d] = sum_t v[t][e]*k[t][d]*kdec[t] ----------------
__global__ __launch_bounds__(256, 4) void chunk_kv_kernel(const bf16* __restrict__ qkv, bf16* __restrict__ Cout) {
    const int j = blockIdx.x, h = blockIdx.y, b = blockIdx.z;
    const int g = h >> 2;
    const float slope = exp2f(-0.5f * (float)(h + 1));
    __shared__ bf16 kdT[64 * 136];
    __shared__ bf16 vT[64 * 136];
    const int tid = threadIdx.x;
#pragma unroll
    for (int p = 0; p < 4; ++p) {
        int flat = p * 256 + tid;
        int t = flat >> 3, d0 = (flat & 7) * 8;
        const size_t row = (size_t)(b * S_ + j * 128 + t);
        uint4 kw = *(const uint4*)(qkv + row * 1536 + 1024 + g * 64 + d0);
        uint4 vw = *(const uint4*)(qkv + row * 1536 + 1280 + g * 64 + d0);
        float kdec = __expf(-slope * (float)(127 - t));
        const bf16* kp = (const bf16*)&kw;
        const bf16* vp = (const bf16*)&vw;
#pragma unroll
        for (int i = 0; i < 8; ++i) {
            int e = d0 + i;
            int sw = (((t >> 3) & ~7) << 3) + ((((t >> 3) ^ (e >> 3)) & 7) << 3) + (t & 7);
            kdT[e * 136 + sw] = __float2bfloat16(__bfloat162float(kp[i]) * kdec);
            vT[e * 136 + sw] = vp[i];
        }
    }
    __syncthreads();
    const int wave = tid >> 6, lane = tid & 63, lr = lane & 15, quad = lane >> 4;
    const int ew = wave * 16;
    f32x4 acc[4] = {};
#pragma unroll
    for (int ks = 0; ks < 128; ks += 32) {
        int qa = (ks >> 3) + quad;
        int qhi = (qa & ~7) << 3;
        int ea = ew + lr;
        bf16x8 a = *(const bf16x8*)(&vT[ea * 136 + qhi + (((qa ^ (ea >> 3)) & 7) << 3)]);
#pragma unroll
        for (int ni = 0; ni < 4; ++ni) {
            int eb = ni * 16 + lr;
            bf16x8 bb = *(const bf16x8*)(&kdT[eb * 136 + qhi + (((qa ^ (eb >> 3)) & 7) << 3)]);
            acc[ni] = __builtin_amdgcn_mfma_f32_16x16x32_bf16(a, bb, acc[ni], 0, 0, 0);
        }
    }
    bf16* out = Cout + ((size_t)((b * NH_ + h) * NC_ + j)) * 4096;
#pragma unroll
    for (int ni = 0; ni < 4; ++ni)
#pragma unroll
        for (int r = 0; r < 4; ++r)
            out[(ew + quad * 4 + r) * 64 + ni * 16 + lr] = __float2bfloat16(acc[ni][r]);
}

// ---------------- exclusive decay scan: one (bh,e,d) lane per thread, coalesced ----------------
__global__ __launch_bounds__(256) void scan_kv_kernel(const bf16* __restrict__ Cin, bf16* __restrict__ st) {
    const int bh = blockIdx.x >> 4;                       // 16 blocks per bh
    const int f = ((blockIdx.x & 15) << 8) + threadIdx.x; // 0..4095
    const int h = bh & (NH_ - 1);
    const float slope = exp2f(-0.5f * (float)(h + 1));
    const float bdec = __expf(-slope * 128.0f);
    const bf16* Cb = Cin + (size_t)bh * NC_ * 4096 + f;
    bf16* sb = st + (size_t)bh * NC_ * 4096 + f;
    float carry = 0.f;
#pragma unroll 8
    for (int c = 0; c < NC_; ++c) {
        sb[(size_t)c * 4096] = __float2bfloat16(carry);
        carry = bdec * carry + __bfloat162float(Cb[(size_t)c * 4096]);
    }
}

// ---------------- per-chunk output: O = (mask ∘ qk^T) v + (q*qdec) kv ----------------
// LDS overlay: phase1 {qs[128][72], k[128][72]} = 18432 elems; phase2 {Ps[128][136],
// vT[64][136]} = 26112 elems. Union 26112 elems = 52.2 KB -> 3 blocks/CU.
__global__ __launch_bounds__(256, 3) void attn_chunk_kernel(const bf16* __restrict__ qkv,
                                                            const bf16* __restrict__ kvst,
                                                            bf16* __restrict__ outb) {
    const int c = blockIdx.x, h = blockIdx.y, b = blockIdx.z;
    const int g = h >> 2;
    const float slope = exp2f(-0.5f * (float)(h + 1));
    __shared__ bf16 smem[26112];
    bf16* qs  = smem;            // phase1: [128][72]
    bf16* kbs = smem + 9216;     // phase1: [128][72]
    bf16* Ps  = smem;            // phase2: [128][136] swizzled
    bf16* vT  = smem + 17408;    // phase2: [64][136] swizzled
    const int tid = threadIdx.x;
    const int wave = tid >> 6, lane = tid & 63, lr = lane & 15, quad = lane >> 4;
#pragma unroll
    for (int p = 0; p < 4; ++p) {
        int flat = p * 256 + tid;
        int t = flat >> 3, d0 = (flat & 7) * 8;
        size_t row = (size_t)(b * S_ + c * 128 + t);
        *(uint4*)(&qs[t * 72 + d0]) = *(const uint4*)(qkv + row * 1536 + h * 64 + d0);
        *(uint4*)(&kbs[t * 72 + d0]) = *(const uint4*)(qkv + row * 1536 + 1024 + g * 64 + d0);
    }
    __syncthreads();
    const int m0 = wave * 32;
    f32x4 sacc[2][8] = {};
#pragma unroll
    for (int kk = 0; kk < 64; kk += 32) {
        bf16x8 af0 = *(const bf16x8*)(&qs[(m0 + lr) * 72 + kk + quad * 8]);
        bf16x8 af1 = *(const bf16x8*)(&qs[(m0 + 16 + lr) * 72 + kk + quad * 8]);
#pragma unroll
        for (int ni = 0; ni < 8; ++ni) {
            bf16x8 bfr = *(const bf16x8*)(&kbs[(ni * 16 + lr) * 72 + kk + quad * 8]);
            sacc[0][ni] = __builtin_amdgcn_mfma_f32_16x16x32_bf16(af0, bfr, sacc[0][ni], 0, 0, 0);
            sacc[1][ni] = __builtin_amdgcn_mfma_f32_16x16x32_bf16(af1, bfr, sacc[1][ni], 0, 0, 0);
        }
    }
    // qKV term first (qs still live; global kv-state loads overlap)
    f32x4 oacc[2][4] = {};
    const bf16* kvb = kvst + ((size_t)((b * NH_ + h) * NC_ + c)) * 4096;
    float qd0 = __expf(-slope * (float)(m0 + lr + 1));
    float qd1 = __expf(-slope * (float)(m0 + 16 + lr + 1));
#pragma unroll
    for (int kk = 0; kk < 64; kk += 32) {
        bf16x8 a0 = *(const bf16x8*)(&qs[(m0 + lr) * 72 + kk + quad * 8]);
        bf16x8 a1 = *(const bf16x8*)(&qs[(m0 + 16 + lr) * 72 + kk + quad * 8]);
#pragma unroll
        for (int i = 0; i < 8; ++i) {
            a0[i] = (__bf16)((float)a0[i] * qd0);
            a1[i] = (__bf16)((float)a1[i] * qd1);
        }
#pragma unroll
        for (int ni = 0; ni < 4; ++ni) {
            bf16x8 bk = *(const bf16x8*)(kvb + (ni * 16 + lr) * 64 + kk + quad * 8);
            oacc[0][ni] = __builtin_amdgcn_mfma_f32_16x16x32_bf16(a0, bk, oacc[0][ni], 0, 0, 0);
            oacc[1][ni] = __builtin_amdgcn_mfma_f32_16x16x32_bf16(a1, bk, oacc[1][ni], 0, 0, 0);
        }
    }
    __syncthreads();  // qs/kbs fully consumed; region reused for Ps/vT
    // factorized mask: exp(-s*(t-tp)) = exp(-s*(t-m0)) * exp(-s*max(m0-tp,-31))
    float ftv[2][4], gtv[8];
#pragma unroll
    for (int mi = 0; mi < 2; ++mi)
#pragma unroll
        for (int r = 0; r < 4; ++r) ftv[mi][r] = __expf(-slope * (float)(mi * 16 + quad * 4 + r));
#pragma unroll
    for (int ni = 0; ni < 8; ++ni)
        gtv[ni] = __expf(-slope * fmaxf((float)(m0 - (ni * 16 + lr)), -31.0f));
#pragma unroll
    for (int mi = 0; mi < 2; ++mi)
#pragma unroll
        for (int ni = 0; ni < 8; ++ni)
#pragma unroll
            for (int r = 0; r < 4; ++r) {
                int t = m0 + mi * 16 + quad * 4 + r;
                int tp = ni * 16 + lr;
                float val = (t >= tp) ? sacc[mi][ni][r] * ftv[mi][r] * gtv[ni] : 0.f;
                int sw = (((tp >> 3) & ~7) << 3) + ((((tp >> 3) ^ (t >> 3)) & 7) << 3) + (tp & 7);
                Ps[t * 136 + sw] = __float2bfloat16(val);
            }
    // stage v transposed (swizzled)
#pragma unroll
    for (int p = 0; p < 4; ++p) {
        int flat = p * 256 + tid;
        int t = flat >> 3, d0 = (flat & 7) * 8;
        size_t row = (size_t)(b * S_ + c * 128 + t);
        uint4 vw = *(const uint4*)(qkv + row * 1536 + 1280 + g * 64 + d0);
        const bf16* vp = (const bf16*)&vw;
#pragma unroll
        for (int i = 0; i < 8; ++i) {
            int e = d0 + i;
            int sw = (((t >> 3) & ~7) << 3) + ((((t >> 3) ^ (e >> 3)) & 7) << 3) + (t & 7);
            vT[e * 136 + sw] = vp[i];
        }
    }
    __syncthreads();
#pragma unroll
    for (int ks2 = 0; ks2 < 128; ks2 += 32) {
        int qa = (ks2 >> 3) + quad;             // chunk index 0..15
        int qhi = (qa & ~7) << 3;
        int ra0 = m0 + lr, ra1 = m0 + 16 + lr;
        bf16x8 af0 = *(const bf16x8*)(&Ps[ra0 * 136 + qhi + (((qa ^ (ra0 >> 3)) & 7) << 3)]);
        bf16x8 af1 = *(const bf16x8*)(&Ps[ra1 * 136 + qhi + (((qa ^ (ra1 >> 3)) & 7) << 3)]);
#pragma unroll
        for (int ni = 0; ni < 4; ++ni) {
            int eb = ni * 16 + lr;
            bf16x8 bfv = *(const bf16x8*)(&vT[eb * 136 + qhi + (((qa ^ (eb >> 3)) & 7) << 3)]);
            oacc[0][ni] = __builtin_amdgcn_mfma_f32_16x16x32_bf16(af0, bfv, oacc[0][ni], 0, 0, 0);
            oacc[1][ni] = __builtin_amdgcn_mfma_f32_16x16x32_bf16(af1, bfv, oacc[1][ni], 0, 0, 0);
        }
    }
#pragma unroll
    for (int mi = 0; mi < 2; ++mi)
#pragma unroll
        for (int ni = 0; ni < 4; ++ni)
#pragma unroll
            for (int r = 0; r < 4; ++r) {
                int t = m0 + mi * 16 + quad * 4 + r;
                int e = ni * 16 + lr;
                size_t row = (size_t)(b * S_ + c * 128 + t);
                outb[row * (NH_ * 64) + h * 64 + e] = __float2bfloat16(oacc[mi][ni][r]);
            }
}

extern "C" void kernel_launch(void* const* d_in, const int* in_sizes, int n_in,
                              void* d_out, int out_size, void* d_ws, size_t ws_size,
                              hipStream_t stream) {
    (void)in_sizes; (void)n_in; (void)out_size; (void)ws_size;
    const float* x  = (const float*)d_in[0];
    const float* Wq = (const float*)d_in[1];
    const float* Wk = (const float*)d_in[2];
    const float* Wv = (const float*)d_in[3];
    const float* Wo = (const float*)d_in[4];
    float* out = (float*)d_out;
    char* ws = (char*)d_ws;
    bf16*  xb    = (bf16*)(ws);                    // 33,554,432 (reused as attn_out)
    bf16*  qkvb  = (bf16*)(ws + 33554432);         // 50,331,648  [M][1536]: q|k|v
    bf16*  wqkvb = (bf16*)(ws + 83886080);         //  3,145,728  [1536][1024]
    bf16*  wob   = (bf16*)(ws + 87031808);         //  2,097,152
    float* cosd  = (float*)(ws + 89128960);        //  1,048,576
    float* sind  = (float*)(ws + 90177536);        //  1,048,576
    bf16*  Cbuf  = (bf16*)(ws + 91226112);         // 16,777,216
    bf16*  kvst  = (bf16*)(ws + 108003328);        // 16,777,216  -> total 124,780,544 B
    bf16*  attn  = xb;

    prep_kernel<<<19968, 256, 0, stream>>>(x, Wq, Wk, Wv, Wo, xb, wqkvb, wob, cosd, sind);

    // fused q|k|v projection with RoPE on cols < 1280 (q heads + k heads), 256^2 8-phase
    gemm256_kernel<bf16><<<dim3(64, 6), 512, 0, stream>>>(xb, wqkvb, qkvb, 1536, 1280, cosd, sind);

    chunk_kv_kernel<<<dim3(NC_, NH_, B_), 256, 0, stream>>>(qkvb, Cbuf);
    scan_kv_kernel<<<512, 256, 0, stream>>>(Cbuf, kvst);
    attn_chunk_kernel<<<dim3(NC_, NH_, B_), 256, 0, stream>>>(qkvb, kvst, attn);

    // output projection, 256^2 8-phase (perfect 256-block wave: 1 block/CU)
    gemm256_kernel<float><<<dim3(64, 4), 512, 0, stream>>>(attn, wob, out, 1024, 0, cosd, sind);
}

// Round 2
// 270.926 us; speedup vs baseline: 1.0113x; 1.0113x over previous
//
#include <hip/hip_runtime.h>
#include <hip/hip_bf16.h>

#define B_ 2
#define S_ 8192
#define DIM_ 1024
#define NH_ 16
#define NKV_ 4
#define HD_ 64
#define NC_ 64

typedef __bf16 bf16x8 __attribute__((ext_vector_type(8)));
typedef float f32x4 __attribute__((ext_vector_type(4)));
using bf16 = __hip_bfloat16;

// async global->LDS, 16B per lane; LDS dst = base + lane*16 (wave-uniform base)
#define ASYNC16(gp, lp) __builtin_amdgcn_global_load_lds( \
    (__attribute__((address_space(1))) void*)(void*)(gp), \
    (__attribute__((address_space(3))) void*)(void*)(lp), 16, 0, 0)

// ---------------- fused prep: x->bf16, weights->bf16, rope tables ----------------
__global__ __launch_bounds__(256) void prep_kernel(const float* __restrict__ x, const float* __restrict__ Wq,
                                                   const float* __restrict__ Wk, const float* __restrict__ Wv,
                                                   const float* __restrict__ Wo, bf16* __restrict__ xb,
                                                   bf16* __restrict__ wqkv, bf16* __restrict__ wo,
                                                   float* __restrict__ cosd, float* __restrict__ sind) {
    int bid = blockIdx.x;
    if (bid < 16384) {  // x convert: 16,777,216 elems
        size_t i = ((size_t)bid * 256 + threadIdx.x) * 4;
        const float4 f = *(const float4*)(x + i);
        bf16 t[4];
        t[0] = __float2bfloat16(f.x); t[1] = __float2bfloat16(f.y);
        t[2] = __float2bfloat16(f.z); t[3] = __float2bfloat16(f.w);
        *(uint2*)(xb + i) = *(const uint2*)t;
    } else if (bid < 18944) {  // weights: Wq|Wk|Wv -> wqkv, Wo -> wo
        size_t e = ((size_t)(bid - 16384) * 256 + threadIdx.x) * 4;
        const float* src;
        bf16* dst;
        if (e < 1048576)        { src = Wq + e;             dst = wqkv + e; }
        else if (e < 1310720)   { src = Wk + (e - 1048576); dst = wqkv + e; }
        else if (e < 1572864)   { src = Wv + (e - 1310720); dst = wqkv + e; }
        else                    { src = Wo + (e - 1572864); dst = wo + (e - 1572864); }
        const float4 f = *(const float4*)src;
        bf16 t[4];
        t[0] = __float2bfloat16(f.x); t[1] = __float2bfloat16(f.y);
        t[2] = __float2bfloat16(f.z); t[3] = __float2bfloat16(f.w);
        *(uint2*)dst = *(const uint2*)t;
    } else {  // rope tables: S_*32 entries, f64 range-reduction + hw sin/cos
        int idx = (bid - 18944) * 256 + threadIdx.x;
        int s = idx >> 5, i = idx & 31;
        double inv = exp((double)i * (-9.210340371976184 / 32.0));  // 10000^(-i/32)
        double rev = ((double)s * inv) * 0.15915494309189535;       // angle / 2pi
        double frac = rev - floor(rev);
        float a = (float)frac * 6.2831853071795865f;
        cosd[idx] = __cosf(a);
        sind[idx] = __sinf(a);
    }
}

// ---------------- 256x256-tile 8-phase GEMM: C[M][N] = A[M][1024] * B[N][1024]^T ----------------
// T3+T4+T5, template-exact (m201): 512 thr = 8 waves (2M x 4N), per-wave C = 128x64.
// LDS 128 KiB: As/Bs[2 bufs][256][64] bf16, XOR chunk-swizzle via pre-swizzled GLOBAL source.
// Per phase (NO sched_barriers anywhere -- R1 post-mortem: 16 sched_barrier(0)/iter was the
// m141 order-pinning regression, MfmaUtil 27%):
//   [ds_reads][stage half-tile][opt lgkmcnt(8) if 12 reads] s_barrier; lgkmcnt(0);
//   setprio(1); 16 MFMA; setprio(0); s_barrier.
// Stage slots (region dead at stage time; verified race-free R1, refcheck passed):
//   P1 b1.A.lo(t1) | P2 b1.A.hi(t1) | P3 b0.B.lo(t+2) | P4 b0.A.lo + vmcnt(4)
//   P5 b0.A.hi | P6 b0.B.hi | P7 b1.B.lo(t1+2) | P8 b1.B.hi + vmcnt(4)
// vmcnt(4) accounting: at P4 wait, queue=[pP7,pP8,P1,P2,P3,P4]x2=12 -> oldest 8 complete =
// buf1 B (pP7/pP8) + buf1 A (P1/P2), ready for P5/P7 reads. At P8 wait, queue=[P3..P8]x2=12 ->
// oldest 8 = all buf0 halves complete before next P1. Never drained to 0 in main loop.
template <typename OT>
__global__ __launch_bounds__(512, 1) void gemm256_kernel(const bf16* __restrict__ A, const bf16* __restrict__ Bm,
                                                         OT* __restrict__ C, int N, int rope_ncols,
                                                         const float* __restrict__ cosd,
                                                         const float* __restrict__ sind) {
    __shared__ bf16 As[2][16384];   // [buf][256 rows][64 cols]
    __shared__ bf16 Bs[2][16384];
    const int tid = threadIdx.x;
    const int wave = tid >> 6, lane = tid & 63;
    const int wr = wave >> 2, wc = wave & 3;
    const int wm = wr * 128, wn = wc * 64;
    const int lr = lane & 15, quad = lane >> 4;
    const int bm = blockIdx.x * 256, bn = blockIdx.y * 256;
    // staging geometry: each wave covers 16 rows per half-tile via 2 loads (8 rows each);
    // global source column pre-swizzled so linear LDS ends up chunk-XOR'd by (row&7).
    const int sub0 = wave * 2, sub1 = sub0 + 1;
    const int rr = lane >> 3;                 // row within 8-row group
    const int cc = ((lane & 7) ^ rr) * 8;     // swizzled source chunk (elems)
    const bf16* Ab = A + (size_t)(bm + rr) * 1024 + cc;
    const bf16* Bb = Bm + (size_t)(bn + rr) * 1024 + cc;

#define STG(dst, base, half, k0)                                                                        \
    do {                                                                                                \
        ASYNC16((base) + (size_t)((half) * 128 + sub0 * 8) * 1024 + (k0), &(dst)[(half) * 8192 + sub0 * 512]); \
        ASYNC16((base) + (size_t)((half) * 128 + sub1 * 8) * 1024 + (k0), &(dst)[(half) * 8192 + sub1 * 512]); \
    } while (0)

#define RD_A(c, mbase)                                                                                  \
    do {                                                                                                \
        _Pragma("unroll") for (int mi_ = 0; mi_ < 4; ++mi_)                                             \
            _Pragma("unroll") for (int kx_ = 0; kx_ < 2; ++kx_)                                         \
                af[mi_][kx_] = *(const bf16x8*)&As[c][(wm + (mbase) + mi_ * 16 + lr) * 64 +              \
                                                     ((kx_ * 4 + quad) ^ (lr & 7)) * 8];                \
    } while (0)

#define RD_B2(c, n0)                                                                                    \
    do {                                                                                                \
        _Pragma("unroll") for (int ni_ = 0; ni_ < 2; ++ni_)                                             \
            _Pragma("unroll") for (int kx_ = 0; kx_ < 2; ++kx_)                                         \
                bfr[(n0) + ni_][kx_] = *(const bf16x8*)&Bs[c][(wn + ((n0) + ni_) * 16 + lr) * 64 +      \
                                                              ((kx_ * 4 + quad) ^ (lr & 7)) * 8];       \
    } while (0)

// opening barrier + full LDS drain, then prioritized MFMA cluster, then closing barrier
#define MM(mo, n0)                                                                                      \
    do {                                                                                                \
        __builtin_amdgcn_s_barrier();                                                                   \
        asm volatile("s_waitcnt lgkmcnt(0)");                                                           \
        __builtin_amdgcn_s_setprio(1);                                                                  \
        _Pragma("unroll") for (int kx_ = 0; kx_ < 2; ++kx_)                                             \
            _Pragma("unroll") for (int mi_ = 0; mi_ < 4; ++mi_)                                         \
                _Pragma("unroll") for (int ni_ = 0; ni_ < 2; ++ni_)                                     \
                    acc[(mo) + mi_][(n0) + ni_] = __builtin_amdgcn_mfma_f32_16x16x32_bf16(              \
                        af[mi_][kx_], bfr[(n0) + ni_][kx_], acc[(mo) + mi_][(n0) + ni_], 0, 0, 0);      \
        __builtin_amdgcn_s_setprio(0);                                                                  \
        __builtin_amdgcn_s_barrier();                                                                   \
    } while (0)

#define GQ_ITER(K1, K2, K3, LAST)                                                                       \
    do {                                                                                                \
        /* P1 */ RD_A(0, 0); RD_B2(0, 0); STG(As[1], Ab, 0, (K1));                                      \
                 asm volatile("s_waitcnt lgkmcnt(8)");                                                  \
                 MM(0, 0);                                                                              \
        /* P2 */ RD_B2(0, 2); STG(As[1], Ab, 1, (K1)); MM(0, 2);                                        \
        /* P3 */ RD_A(0, 64); if (!(LAST)) { STG(Bs[0], Bb, 0, (K2)); } MM(4, 0);                       \
        /* P4 */ if (!(LAST)) { STG(As[0], Ab, 0, (K2)); asm volatile("s_waitcnt vmcnt(4)"); }          \
                 else { asm volatile("s_waitcnt vmcnt(0)"); }                                           \
                 MM(4, 2);                                                                              \
        /* P5 */ RD_A(1, 0); RD_B2(1, 0); if (!(LAST)) { STG(As[0], Ab, 1, (K2)); }                     \
                 asm volatile("s_waitcnt lgkmcnt(8)");                                                  \
                 MM(0, 0);                                                                              \
        /* P6 */ RD_B2(1, 2); if (!(LAST)) { STG(Bs[0], Bb, 1, (K2)); } MM(0, 2);                       \
        /* P7 */ RD_A(1, 64); if (!(LAST)) { STG(Bs[1], Bb, 0, (K3)); } MM(4, 0);                       \
        /* P8 */ if (!(LAST)) { STG(Bs[1], Bb, 1, (K3)); asm volatile("s_waitcnt vmcnt(4)"); }          \
                 MM(4, 2);                                                                              \
    } while (0)

    f32x4 acc[8][4] = {};
    bf16x8 af[4][2];    // current A m-frag half (m0-3 or m4-7) x kk
    bf16x8 bfr[4][2];   // B n-frags 0..3 x kk

    // prologue: tile0 -> buf0 (order B.lo, A.lo, A.hi, B.hi), tile1 B halves -> buf1.
    // vmcnt(4): tile0's 8 loads landed, tile1's B (last 4) may stay in flight.
    STG(Bs[0], Bb, 0, 0); STG(As[0], Ab, 0, 0); STG(As[0], Ab, 1, 0); STG(Bs[0], Bb, 1, 0);
    STG(Bs[1], Bb, 0, 64); STG(Bs[1], Bb, 1, 64);
    asm volatile("s_waitcnt vmcnt(4)");
    __builtin_amdgcn_s_barrier();

    for (int i = 0; i < 7; ++i) {
        GQ_ITER(i * 128 + 64, i * 128 + 128, i * 128 + 192, 0);
    }
    GQ_ITER(960, 0, 0, 1);

    if (bn + wn < rope_ncols) {
        // wave's 64 columns = exactly one head; pair (i, i+32) = (acc[mi][ni], acc[mi][ni+2])
#pragma unroll
        for (int mi = 0; mi < 8; ++mi)
#pragma unroll
            for (int r = 0; r < 4; ++r) {
                int row = bm + wm + mi * 16 + quad * 4 + r;
                int s = row & (S_ - 1);
#pragma unroll
                for (int ni = 0; ni < 2; ++ni) {
                    int ii = ni * 16 + lr;
                    float cs = cosd[(s << 5) + ii];
                    float sn = sind[(s << 5) + ii];
                    float x1 = acc[mi][ni][r], x2 = acc[mi][ni + 2][r];
                    acc[mi][ni][r] = x1 * cs - x2 * sn;
                    acc[mi][ni + 2][r] = x2 * cs + x1 * sn;
                }
            }
    }
#pragma unroll
    for (int mi = 0; mi < 8; ++mi)
#pragma unroll
        for (int ni = 0; ni < 4; ++ni)
#pragma unroll
            for (int r = 0; r < 4; ++r) {
                int row = bm + wm + mi * 16 + quad * 4 + r;
                int col = bn + wn + ni * 16 + lr;
                float v = acc[mi][ni][r];
                if constexpr (__is_same(OT, float)) C[(size_t)row * N + col] = v;
                else C[(size_t)row * N + col] = __float2bfloat16(v);
            }
#undef STG
#undef RD_A
#undef RD_B2
#undef MM
#undef GQ_ITER
}

// XOR chunk swizzle for transposed LDS tiles (row stride 136 elems, b128-aligned):
// element (row e, col t): addr = e*136 + ((chunk & ~7)<<3) + (((chunk ^ (e>>3)) & 7)<<3) + (t&7),
// chunk = t>>3. Bit 3 of chunk MUST be kept (cols 0..127 -> chunk 0..15); dropping it
// aliases t and t+64 (the R4 NaN bug). Transpose stores hit 8 distinct banks; b128 reads aligned.

// ---------------- per-chunk KV contribution: CT[e][d] = sum_t v[t][e]*k[t][d]*kdec[t] ----------------
__global__ __launch_bounds__(256, 4) void chunk_kv_kernel(const bf16* __restrict__ qkv, bf16* __restrict__ Cout) {
    const int j = blockIdx.x, h = blockIdx.y, b = blockIdx.z;
    const int g = h >> 2;
    const float slope = exp2f(-0.5f * (float)(h + 1));
    __shared__ bf16 kdT[64 * 136];
    __shared__ bf16 vT[64 * 136];
    const int tid = threadIdx.x;
#pragma unroll
    for (int p = 0; p < 4; ++p) {
        int flat = p * 256 + tid;
        int t = flat >> 3, d0 = (flat & 7) * 8;
        const size_t row = (size_t)(b * S_ + j * 128 + t);
        uint4 kw = *(const uint4*)(qkv + row * 1536 + 1024 + g * 64 + d0);
        uint4 vw = *(const uint4*)(qkv + row * 1536 + 1280 + g * 64 + d0);
        float kdec = __expf(-slope * (float)(127 - t));
        const bf16* kp = (const bf16*)&kw;
        const bf16* vp = (const bf16*)&vw;
#pragma unroll
        for (int i = 0; i < 8; ++i) {
            int e = d0 + i;
            int sw = (((t >> 3) & ~7) << 3) + ((((t >> 3) ^ (e >> 3)) & 7) << 3) + (t & 7);
            kdT[e * 136 + sw] = __float2bfloat16(__bfloat162float(kp[i]) * kdec);
            vT[e * 136 + sw] = vp[i];
        }
    }
    __syncthreads();
    const int wave = tid >> 6, lane = tid & 63, lr = lane & 15, quad = lane >> 4;
    const int ew = wave * 16;
    f32x4 acc[4] = {};
#pragma unroll
    for (int ks = 0; ks < 128; ks += 32) {
        int qa = (ks >> 3) + quad;
        int qhi = (qa & ~7) << 3;
        int ea = ew + lr;
        bf16x8 a = *(const bf16x8*)(&vT[ea * 136 + qhi + (((qa ^ (ea >> 3)) & 7) << 3)]);
#pragma unroll
        for (int ni = 0; ni < 4; ++ni) {
            int eb = ni * 16 + lr;
            bf16x8 bb = *(const bf16x8*)(&kdT[eb * 136 + qhi + (((qa ^ (eb >> 3)) & 7) << 3)]);
            acc[ni] = __builtin_amdgcn_mfma_f32_16x16x32_bf16(a, bb, acc[ni], 0, 0, 0);
        }
    }
    bf16* out = Cout + ((size_t)((b * NH_ + h) * NC_ + j)) * 4096;
#pragma unroll
    for (int ni = 0; ni < 4; ++ni)
#pragma unroll
        for (int r = 0; r < 4; ++r)
            out[(ew + quad * 4 + r) * 64 + ni * 16 + lr] = __float2bfloat16(acc[ni][r]);
}

// ---------------- exclusive decay scan: one (bh,e,d) lane per thread, coalesced ----------------
__global__ __launch_bounds__(256) void scan_kv_kernel(const bf16* __restrict__ Cin, bf16* __restrict__ st) {
    const int bh = blockIdx.x >> 4;                       // 16 blocks per bh
    const int f = ((blockIdx.x & 15) << 8) + threadIdx.x; // 0..4095
    const int h = bh & (NH_ - 1);
    const float slope = exp2f(-0.5f * (float)(h + 1));
    const float bdec = __expf(-slope * 128.0f);
    const bf16* Cb = Cin + (size_t)bh * NC_ * 4096 + f;
    bf16* sb = st + (size_t)bh * NC_ * 4096 + f;
    float carry = 0.f;
#pragma unroll 8
    for (int c = 0; c < NC_; ++c) {
        sb[(size_t)c * 4096] = __float2bfloat16(carry);
        carry = bdec * carry + __bfloat162float(Cb[(size_t)c * 4096]);
    }
}

// ---------------- per-chunk output: O = (mask ∘ qk^T) v + (q*qdec) kv ----------------
// LDS overlay: phase1 {qs[128][72], k[128][72]} = 18432 elems; phase2 {Ps[128][136],
// vT[64][136]} = 26112 elems. Union 26112 elems = 52.2 KB -> 3 blocks/CU.
__global__ __launch_bounds__(256, 3) void attn_chunk_kernel(const bf16* __restrict__ qkv,
                                                            const bf16* __restrict__ kvst,
                                                            bf16* __restrict__ outb) {
    const int c = blockIdx.x, h = blockIdx.y, b = blockIdx.z;
    const int g = h >> 2;
    const float slope = exp2f(-0.5f * (float)(h + 1));
    __shared__ bf16 smem[26112];
    bf16* qs  = smem;            // phase1: [128][72]
    bf16* kbs = smem + 9216;     // phase1: [128][72]
    bf16* Ps  = smem;            // phase2: [128][136] swizzled
    bf16* vT  = smem + 17408;    // phase2: [64][136] swizzled
    const int tid = threadIdx.x;
    const int wave = tid >> 6, lane = tid & 63, lr = lane & 15, quad = lane >> 4;
#pragma unroll
    for (int p = 0; p < 4; ++p) {
        int flat = p * 256 + tid;
        int t = flat >> 3, d0 = (flat & 7) * 8;
        size_t row = (size_t)(b * S_ + c * 128 + t);
        *(uint4*)(&qs[t * 72 + d0]) = *(const uint4*)(qkv + row * 1536 + h * 64 + d0);
        *(uint4*)(&kbs[t * 72 + d0]) = *(const uint4*)(qkv + row * 1536 + 1024 + g * 64 + d0);
    }
    __syncthreads();
    const int m0 = wave * 32;
    f32x4 sacc[2][8] = {};
#pragma unroll
    for (int kk = 0; kk < 64; kk += 32) {
        bf16x8 af0 = *(const bf16x8*)(&qs[(m0 + lr) * 72 + kk + quad * 8]);
        bf16x8 af1 = *(const bf16x8*)(&qs[(m0 + 16 + lr) * 72 + kk + quad * 8]);
#pragma unroll
        for (int ni = 0; ni < 8; ++ni) {
            bf16x8 bfr = *(const bf16x8*)(&kbs[(ni * 16 + lr) * 72 + kk + quad * 8]);
            sacc[0][ni] = __builtin_amdgcn_mfma_f32_16x16x32_bf16(af0, bfr, sacc[0][ni], 0, 0, 0);
            sacc[1][ni] = __builtin_amdgcn_mfma_f32_16x16x32_bf16(af1, bfr, sacc[1][ni], 0, 0, 0);
        }
    }
    // qKV term first (qs still live; global kv-state loads overlap)
    f32x4 oacc[2][4] = {};
    const bf16* kvb = kvst + ((size_t)((b * NH_ + h) * NC_ + c)) * 4096;
    float qd0 = __expf(-slope * (float)(m0 + lr + 1));
    float qd1 = __expf(-slope * (float)(m0 + 16 + lr + 1));
#pragma unroll
    for (int kk = 0; kk < 64; kk += 32) {
        bf16x8 a0 = *(const bf16x8*)(&qs[(m0 + lr) * 72 + kk + quad * 8]);
        bf16x8 a1 = *(const bf16x8*)(&qs[(m0 + 16 + lr) * 72 + kk + quad * 8]);
#pragma unroll
        for (int i = 0; i < 8; ++i) {
            a0[i] = (__bf16)((float)a0[i] * qd0);
            a1[i] = (__bf16)((float)a1[i] * qd1);
        }
#pragma unroll
        for (int ni = 0; ni < 4; ++ni) {
            bf16x8 bk = *(const bf16x8*)(kvb + (ni * 16 + lr) * 64 + kk + quad * 8);
            oacc[0][ni] = __builtin_amdgcn_mfma_f32_16x16x32_bf16(a0, bk, oacc[0][ni], 0, 0, 0);
            oacc[1][ni] = __builtin_amdgcn_mfma_f32_16x16x32_bf16(a1, bk, oacc[1][ni], 0, 0, 0);
        }
    }
    __syncthreads();  // qs/kbs fully consumed; region reused for Ps/vT
    // factorized mask: exp(-s*(t-tp)) = exp(-s*(t-m0)) * exp(-s*max(m0-tp,-31))
    float ftv[2][4], gtv[8];
#pragma unroll
    for (int mi = 0; mi < 2; ++mi)
#pragma unroll
        for (int r = 0; r < 4; ++r) ftv[mi][r] = __expf(-slope * (float)(mi * 16 + quad * 4 + r));
#pragma unroll
    for (int ni = 0; ni < 8; ++ni)
        gtv[ni] = __expf(-slope * fmaxf((float)(m0 - (ni * 16 + lr)), -31.0f));
#pragma unroll
    for (int mi = 0; mi < 2; ++mi)
#pragma unroll
        for (int ni = 0; ni < 8; ++ni)
#pragma unroll
            for (int r = 0; r < 4; ++r) {
                int t = m0 + mi * 16 + quad * 4 + r;
                int tp = ni * 16 + lr;
                float val = (t >= tp) ? sacc[mi][ni][r] * ftv[mi][r] * gtv[ni] : 0.f;
                int sw = (((tp >> 3) & ~7) << 3) + ((((tp >> 3) ^ (t >> 3)) & 7) << 3) + (tp & 7);
                Ps[t * 136 + sw] = __float2bfloat16(val);
            }
    // stage v transposed (swizzled)
#pragma unroll
    for (int p = 0; p < 4; ++p) {
        int flat = p * 256 + tid;
        int t = flat >> 3, d0 = (flat & 7) * 8;
        size_t row = (size_t)(b * S_ + c * 128 + t);
        uint4 vw = *(const uint4*)(qkv + row * 1536 + 1280 + g * 64 + d0);
        const bf16* vp = (const bf16*)&vw;
#pragma unroll
        for (int i = 0; i < 8; ++i) {
            int e = d0 + i;
            int sw = (((t >> 3) & ~7) << 3) + ((((t >> 3) ^ (e >> 3)) & 7) << 3) + (t & 7);
            vT[e * 136 + sw] = vp[i];
        }
    }
    __syncthreads();
#pragma unroll
    for (int ks2 = 0; ks2 < 128; ks2 += 32) {
        int qa = (ks2 >> 3) + quad;             // chunk index 0..15
        int qhi = (qa & ~7) << 3;
        int ra0 = m0 + lr, ra1 = m0 + 16 + lr;
        bf16x8 af0 = *(const bf16x8*)(&Ps[ra0 * 136 + qhi + (((qa ^ (ra0 >> 3)) & 7) << 3)]);
        bf16x8 af1 = *(const bf16x8*)(&Ps[ra1 * 136 + qhi + (((qa ^ (ra1 >> 3)) & 7) << 3)]);
#pragma unroll
        for (int ni = 0; ni < 4; ++ni) {
            int eb = ni * 16 + lr;
            bf16x8 bfv = *(const bf16x8*)(&vT[eb * 136 + qhi + (((qa ^ (eb >> 3)) & 7) << 3)]);
            oacc[0][ni] = __builtin_amdgcn_mfma_f32_16x16x32_bf16(af0, bfv, oacc[0][ni], 0, 0, 0);
            oacc[1][ni] = __builtin_amdgcn_mfma_f32_16x16x32_bf16(af1, bfv, oacc[1][ni], 0, 0, 0);
        }
    }
#pragma unroll
    for (int mi = 0; mi < 2; ++mi)
#pragma unroll
        for (int ni = 0; ni < 4; ++ni)
#pragma unroll
            for (int r = 0; r < 4; ++r) {
                int t = m0 + mi * 16 + quad * 4 + r;
                int e = ni * 16 + lr;
                size_t row = (size_t)(b * S_ + c * 128 + t);
                outb[row * (NH_ * 64) + h * 64 + e] = __float2bfloat16(oacc[mi][ni][r]);
            }
}

extern "C" void kernel_launch(void* const* d_in, const int* in_sizes, int n_in,
                              void* d_out, int out_size, void* d_ws, size_t ws_size,
                              hipStream_t stream) {
    (void)in_sizes; (void)n_in; (void)out_size; (void)ws_size;
    const float* x  = (const float*)d_in[0];
    const float* Wq = (const float*)d_in[1];
    const float* Wk = (const float*)d_in[2];
    const float* Wv = (const float*)d_in[3];
    const float* Wo = (const float*)d_in[4];
    float* out = (float*)d_out;
    char* ws = (char*)d_ws;
    bf16*  xb    = (bf16*)(ws);                    // 33,554,432 (reused as attn_out)
    bf16*  qkvb  = (bf16*)(ws + 33554432);         // 50,331,648  [M][1536]: q|k|v
    bf16*  wqkvb = (bf16*)(ws + 83886080);         //  3,145,728  [1536][1024]
    bf16*  wob   = (bf16*)(ws + 87031808);         //  2,097,152
    float* cosd  = (float*)(ws + 89128960);        //  1,048,576
    float* sind  = (float*)(ws + 90177536);        //  1,048,576
    bf16*  Cbuf  = (bf16*)(ws + 91226112);         // 16,777,216
    bf16*  kvst  = (bf16*)(ws + 108003328);        // 16,777,216  -> total 124,780,544 B
    bf16*  attn  = xb;

    prep_kernel<<<19968, 256, 0, stream>>>(x, Wq, Wk, Wv, Wo, xb, wqkvb, wob, cosd, sind);

    // fused q|k|v projection with RoPE on cols < 1280 (q heads + k heads), 256^2 8-phase
    gemm256_kernel<bf16><<<dim3(64, 6), 512, 0, stream>>>(xb, wqkvb, qkvb, 1536, 1280, cosd, sind);

    chunk_kv_kernel<<<dim3(NC_, NH_, B_), 256, 0, stream>>>(qkvb, Cbuf);
    scan_kv_kernel<<<512, 256, 0, stream>>>(Cbuf, kvst);
    attn_chunk_kernel<<<dim3(NC_, NH_, B_), 256, 0, stream>>>(qkvb, kvst, attn);

    // output projection, 256^2 8-phase (perfect 256-block wave: 1 block/CU)
    gemm256_kernel<float><<<dim3(64, 4), 512, 0, stream>>>(attn, wob, out, 1024, 0, cosd, sind);
}

// Round 3
// 261.663 us; speedup vs baseline: 1.0471x; 1.0354x over previous
//
#include <hip/hip_runtime.h>
#include <hip/hip_bf16.h>

#define B_ 2
#define S_ 8192
#define DIM_ 1024
#define NH_ 16
#define NKV_ 4
#define HD_ 64
#define NC_ 64

typedef __bf16 bf16x8 __attribute__((ext_vector_type(8)));
typedef float f32x4 __attribute__((ext_vector_type(4)));
using bf16 = __hip_bfloat16;

// async global->LDS, 16B per lane; LDS dst = base + lane*16 (wave-uniform base)
#define ASYNC16(gp, lp) __builtin_amdgcn_global_load_lds( \
    (__attribute__((address_space(1))) void*)(void*)(gp), \
    (__attribute__((address_space(3))) void*)(void*)(lp), 16, 0, 0)

// ---------------- fused prep: x->bf16, weights->bf16, rope tables ----------------
__global__ __launch_bounds__(256) void prep_kernel(const float* __restrict__ x, const float* __restrict__ Wq,
                                                   const float* __restrict__ Wk, const float* __restrict__ Wv,
                                                   const float* __restrict__ Wo, bf16* __restrict__ xb,
                                                   bf16* __restrict__ wqkv, bf16* __restrict__ wo,
                                                   float* __restrict__ cosd, float* __restrict__ sind) {
    int bid = blockIdx.x;
    if (bid < 16384) {  // x convert: 16,777,216 elems
        size_t i = ((size_t)bid * 256 + threadIdx.x) * 4;
        const float4 f = *(const float4*)(x + i);
        bf16 t[4];
        t[0] = __float2bfloat16(f.x); t[1] = __float2bfloat16(f.y);
        t[2] = __float2bfloat16(f.z); t[3] = __float2bfloat16(f.w);
        *(uint2*)(xb + i) = *(const uint2*)t;
    } else if (bid < 18944) {  // weights: Wq|Wk|Wv -> wqkv, Wo -> wo
        size_t e = ((size_t)(bid - 16384) * 256 + threadIdx.x) * 4;
        const float* src;
        bf16* dst;
        if (e < 1048576)        { src = Wq + e;             dst = wqkv + e; }
        else if (e < 1310720)   { src = Wk + (e - 1048576); dst = wqkv + e; }
        else if (e < 1572864)   { src = Wv + (e - 1310720); dst = wqkv + e; }
        else                    { src = Wo + (e - 1572864); dst = wo + (e - 1572864); }
        const float4 f = *(const float4*)src;
        bf16 t[4];
        t[0] = __float2bfloat16(f.x); t[1] = __float2bfloat16(f.y);
        t[2] = __float2bfloat16(f.z); t[3] = __float2bfloat16(f.w);
        *(uint2*)dst = *(const uint2*)t;
    } else {  // rope tables: S_*32 entries, f64 range-reduction + hw sin/cos
        int idx = (bid - 18944) * 256 + threadIdx.x;
        int s = idx >> 5, i = idx & 31;
        double inv = exp((double)i * (-9.210340371976184 / 32.0));  // 10000^(-i/32)
        double rev = ((double)s * inv) * 0.15915494309189535;       // angle / 2pi
        double frac = rev - floor(rev);
        float a = (float)frac * 6.2831853071795865f;
        cosd[idx] = __cosf(a);
        sind[idx] = __sinf(a);
    }
}

// ---------------- C[M][N] = A[M][K]*B[N][K]^T, bf16 in, OT out ----------------
// R2 decision: 128^2 m97-structure is the keeper. 8-phase 256^2 measured 715 TF here
// (2-phase level; K=1024 too short to amortize -- m248's full-stack = 848 TF at this K),
// vs this kernel's proven 876 TF at 3 blocks/CU. Do not revisit without new evidence.
// grid (M/128, N/128): x = M-tile so blocks sharing an A-tile have equal id%8 (same XCD).
// Columns < rope_ncols get RoPE applied in the epilogue (wave-uniform: 64-col strips).
template <typename OT>
__global__ __launch_bounds__(256, 3) void gemm_bt_kernel(const bf16* __restrict__ A, const bf16* __restrict__ Bm,
                                                         OT* __restrict__ C, int M, int N, int K, int rope_ncols,
                                                         const float* __restrict__ cosd,
                                                         const float* __restrict__ sind) {
    __shared__ bf16 As[128 * 64];
    __shared__ bf16 Bs[128 * 64];
    const int tid = threadIdx.x;
    const int bm = blockIdx.x * 128, bn = blockIdx.y * 128;
    const int wave = tid >> 6, lane = tid & 63;
    const int wm = (wave >> 1) * 64, wn = (wave & 1) * 64;
    const int lr = lane & 15, quad = lane >> 4;
    const int srow = wave * 32;
    const int lrow = lane >> 3;                        // 0..7
    const int lchunk = ((lane & 7) ^ lrow) * 8;        // XOR-swizzled source chunk (elems)
    const bf16* Ag = A + (size_t)(bm + srow + lrow) * K + lchunk;
    const bf16* Bg = Bm + (size_t)(bn + srow + lrow) * K + lchunk;
    f32x4 acc[4][4] = {};
    for (int k0 = 0; k0 < K; k0 += 64) {
#pragma unroll
        for (int p = 0; p < 4; ++p) {
            ASYNC16(Ag + (size_t)(p * 8) * K + k0, &As[(srow + p * 8) * 64]);
            ASYNC16(Bg + (size_t)(p * 8) * K + k0, &Bs[(srow + p * 8) * 64]);
        }
        __syncthreads();
#pragma unroll
        for (int kk = 0; kk < 64; kk += 32) {
            const int sw = (((kk >> 3) + quad) ^ (lr & 7)) << 3;  // de-swizzled chunk offset
            bf16x8 af[4], bfr[4];
#pragma unroll
            for (int i = 0; i < 4; ++i) af[i] = *(const bf16x8*)(&As[(wm + i * 16 + lr) * 64 + sw]);
#pragma unroll
            for (int i = 0; i < 4; ++i) bfr[i] = *(const bf16x8*)(&Bs[(wn + i * 16 + lr) * 64 + sw]);
#pragma unroll
            for (int mi = 0; mi < 4; ++mi)
#pragma unroll
                for (int ni = 0; ni < 4; ++ni)
                    acc[mi][ni] = __builtin_amdgcn_mfma_f32_16x16x32_bf16(af[mi], bfr[ni], acc[mi][ni], 0, 0, 0);
        }
        __syncthreads();
    }
    if (bn + wn < rope_ncols) {
        // wave's 64 columns = exactly one head; pair (i, i+32) = (acc[mi][ni], acc[mi][ni+2])
#pragma unroll
        for (int mi = 0; mi < 4; ++mi)
#pragma unroll
            for (int r = 0; r < 4; ++r) {
                int row = bm + wm + mi * 16 + quad * 4 + r;
                int s = row & (S_ - 1);
#pragma unroll
                for (int ni = 0; ni < 2; ++ni) {
                    int i = ni * 16 + lr;
                    float cs = cosd[(s << 5) + i];
                    float sn = sind[(s << 5) + i];
                    float x1 = acc[mi][ni][r], x2 = acc[mi][ni + 2][r];
                    acc[mi][ni][r] = x1 * cs - x2 * sn;
                    acc[mi][ni + 2][r] = x2 * cs + x1 * sn;
                }
            }
    }
#pragma unroll
    for (int mi = 0; mi < 4; ++mi)
#pragma unroll
        for (int ni = 0; ni < 4; ++ni)
#pragma unroll
            for (int r = 0; r < 4; ++r) {
                int row = bm + wm + mi * 16 + quad * 4 + r;
                int col = bn + wn + ni * 16 + lr;
                float v = acc[mi][ni][r];
                if constexpr (__is_same(OT, float)) C[(size_t)row * N + col] = v;
                else C[(size_t)row * N + col] = __float2bfloat16(v);
            }
}

// XOR chunk swizzle for transposed LDS tiles (row stride 136 elems, b128-aligned):
// element (row e, col t): addr = e*136 + ((chunk & ~7)<<3) + (((chunk ^ (e>>3)) & 7)<<3) + (t&7),
// chunk = t>>3. Bit 3 of chunk MUST be kept (cols 0..127 -> chunk 0..15); dropping it
// aliases t and t+64 (the R4 NaN bug). Transpose stores hit 8 distinct banks; b128 reads aligned.

// ---------------- per-chunk KV contribution, PER-GROUP: all 4 heads of group g ----------------
// C_h[e][d] = sum_t v[t][e]*kdec_h[t]*k[t][d]. kdec multiplies along the MFMA K-dim (t), so it
// attaches to EITHER operand; moving it to the v-side A-frag lets k/v be staged RAW and ONCE
// per group (was 4x redundant per-head staging). 512 thr = 8 waves: wave w -> e-block
// (w&3)*16, head-pair (w>>2)*2. A-frag t-mapping: frag at chunk qa holds t = qa*8 + i
// (i=0..7), qa = (ks>>3)+quad -> kdec(t) = exp(-slope*(127-ks-quad*8)) * exp(slope)^i,
// applied as serial multiply chain in f32, rounded to bf16 (same rounding class as the old
// k-side bf16 product). LDS 34.8 KB -> 4 blocks/CU (32 waves).
__global__ __launch_bounds__(512) void chunk_kv_kernel(const bf16* __restrict__ qkv, bf16* __restrict__ Cout) {
    const int j = blockIdx.x, g = blockIdx.y, b = blockIdx.z;
    __shared__ bf16 kT[64 * 136];
    __shared__ bf16 vT[64 * 136];
    const int tid = threadIdx.x;
#pragma unroll
    for (int p = 0; p < 2; ++p) {
        int flat = p * 512 + tid;
        int t = flat >> 3, d0 = (flat & 7) * 8;
        const size_t row = (size_t)(b * S_ + j * 128 + t);
        uint4 kw = *(const uint4*)(qkv + row * 1536 + 1024 + g * 64 + d0);
        uint4 vw = *(const uint4*)(qkv + row * 1536 + 1280 + g * 64 + d0);
        const bf16* kp = (const bf16*)&kw;
        const bf16* vp = (const bf16*)&vw;
#pragma unroll
        for (int i = 0; i < 8; ++i) {
            int e = d0 + i;
            int sw = (((t >> 3) & ~7) << 3) + ((((t >> 3) ^ (e >> 3)) & 7) << 3) + (t & 7);
            kT[e * 136 + sw] = kp[i];
            vT[e * 136 + sw] = vp[i];
        }
    }
    __syncthreads();
    const int wave = tid >> 6, lane = tid & 63, lr = lane & 15, quad = lane >> 4;
    const int eblk = (wave & 3) * 16;
    const int hp = (wave >> 2) * 2;   // heads g*4+hp, g*4+hp+1
    f32x4 acc[2][4] = {};
    float slope[2], g1[2];
#pragma unroll
    for (int hh = 0; hh < 2; ++hh) {
        slope[hh] = exp2f(-0.5f * (float)(g * 4 + hp + hh + 1));
        g1[hh] = __expf(slope[hh]);
    }
#pragma unroll
    for (int ks = 0; ks < 128; ks += 32) {
        int qa = (ks >> 3) + quad;
        int qhi = (qa & ~7) << 3;
        int ea = eblk + lr;
        bf16x8 a = *(const bf16x8*)(&vT[ea * 136 + qhi + (((qa ^ (ea >> 3)) & 7) << 3)]);
        float av[8];
#pragma unroll
        for (int i = 0; i < 8; ++i) av[i] = (float)a[i];
        bf16x8 bb[4];
#pragma unroll
        for (int ni = 0; ni < 4; ++ni) {
            int eb = ni * 16 + lr;
            bb[ni] = *(const bf16x8*)(&kT[eb * 136 + qhi + (((qa ^ (eb >> 3)) & 7) << 3)]);
        }
#pragma unroll
        for (int hh = 0; hh < 2; ++hh) {
            float m = __expf(-slope[hh] * (float)(127 - ks - quad * 8));
            bf16x8 as;
#pragma unroll
            for (int i = 0; i < 8; ++i) { as[i] = (__bf16)(av[i] * m); m *= g1[hh]; }
#pragma unroll
            for (int ni = 0; ni < 4; ++ni)
                acc[hh][ni] = __builtin_amdgcn_mfma_f32_16x16x32_bf16(as, bb[ni], acc[hh][ni], 0, 0, 0);
        }
    }
#pragma unroll
    for (int hh = 0; hh < 2; ++hh) {
        int h = g * 4 + hp + hh;
        bf16* out = Cout + ((size_t)((b * NH_ + h) * NC_ + j)) * 4096;
#pragma unroll
        for (int ni = 0; ni < 4; ++ni)
#pragma unroll
            for (int r = 0; r < 4; ++r)
                out[(eblk + quad * 4 + r) * 64 + ni * 16 + lr] = __float2bfloat16(acc[hh][ni][r]);
    }
}

// ---------------- exclusive decay scan: one (bh,e,d) lane per thread, coalesced ----------------
__global__ __launch_bounds__(256) void scan_kv_kernel(const bf16* __restrict__ Cin, bf16* __restrict__ st) {
    const int bh = blockIdx.x >> 4;                       // 16 blocks per bh
    const int f = ((blockIdx.x & 15) << 8) + threadIdx.x; // 0..4095
    const int h = bh & (NH_ - 1);
    const float slope = exp2f(-0.5f * (float)(h + 1));
    const float bdec = __expf(-slope * 128.0f);
    const bf16* Cb = Cin + (size_t)bh * NC_ * 4096 + f;
    bf16* sb = st + (size_t)bh * NC_ * 4096 + f;
    float carry = 0.f;
#pragma unroll 8
    for (int c = 0; c < NC_; ++c) {
        sb[(size_t)c * 4096] = __float2bfloat16(carry);
        carry = bdec * carry + __bfloat162float(Cb[(size_t)c * 4096]);
    }
}

// ---------------- per-chunk output: O = (mask ∘ qk^T) v + (q*qdec) kv ----------------
// q/k now staged via chunk-XOR pre-swizzled ASYNC16 into linear [128][64] tiles (the gemm's
// proven 0-conflict pattern) instead of global->reg->LDS with stride-72 pad. Read addr:
// [t*64 + ((chunk ^ (t&7))<<3)], chunk = (kk>>3)+quad; all read sites have t&7 == lr&7.
// LDS overlay: phase1 {qs[128][64], kbs[128][64]} = 16384 elems; phase2 {Ps[128][136],
// vT[64][136]} = 26112 elems. Union 26112 elems = 52.2 KB -> 3 blocks/CU.
__global__ __launch_bounds__(256, 3) void attn_chunk_kernel(const bf16* __restrict__ qkv,
                                                            const bf16* __restrict__ kvst,
                                                            bf16* __restrict__ outb) {
    const int c = blockIdx.x, h = blockIdx.y, b = blockIdx.z;
    const int g = h >> 2;
    const float slope = exp2f(-0.5f * (float)(h + 1));
    __shared__ bf16 smem[26112];
    bf16* qs  = smem;            // phase1: [128][64] chunk-XOR swizzled
    bf16* kbs = smem + 8192;     // phase1: [128][64] chunk-XOR swizzled
    bf16* Ps  = smem;            // phase2: [128][136] swizzled
    bf16* vT  = smem + 17408;    // phase2: [64][136] swizzled
    const int tid = threadIdx.x;
    const int wave = tid >> 6, lane = tid & 63, lr = lane & 15, quad = lane >> 4;
    const int srow = lane >> 3;                  // 0..7
    const int schunk = ((lane & 7) ^ srow) * 8;  // pre-swizzled source chunk (elems)
#pragma unroll
    for (int p = 0; p < 4; ++p) {
        int t0 = wave * 8 + p * 32;
        size_t row = (size_t)(b * S_ + c * 128 + t0 + srow);
        ASYNC16(qkv + row * 1536 + h * 64 + schunk, &qs[t0 * 64]);
        ASYNC16(qkv + row * 1536 + 1024 + g * 64 + schunk, &kbs[t0 * 64]);
    }
    asm volatile("s_waitcnt vmcnt(0)");
    __syncthreads();
    const int m0 = wave * 32;
    f32x4 sacc[2][8] = {};
#pragma unroll
    for (int kk = 0; kk < 64; kk += 32) {
        const int sw = ((((kk >> 3) + quad) ^ (lr & 7)) & 7) << 3;
        bf16x8 af0 = *(const bf16x8*)(&qs[(m0 + lr) * 64 + sw]);
        bf16x8 af1 = *(const bf16x8*)(&qs[(m0 + 16 + lr) * 64 + sw]);
#pragma unroll
        for (int ni = 0; ni < 8; ++ni) {
            bf16x8 bfr = *(const bf16x8*)(&kbs[(ni * 16 + lr) * 64 + sw]);
            sacc[0][ni] = __builtin_amdgcn_mfma_f32_16x16x32_bf16(af0, bfr, sacc[0][ni], 0, 0, 0);
            sacc[1][ni] = __builtin_amdgcn_mfma_f32_16x16x32_bf16(af1, bfr, sacc[1][ni], 0, 0, 0);
        }
    }
    // qKV term (qs still live; global kv-state loads overlap)
    f32x4 oacc[2][4] = {};
    const bf16* kvb = kvst + ((size_t)((b * NH_ + h) * NC_ + c)) * 4096;
    float qd0 = __expf(-slope * (float)(m0 + lr + 1));
    float qd1 = __expf(-slope * (float)(m0 + 16 + lr + 1));
#pragma unroll
    for (int kk = 0; kk < 64; kk += 32) {
        const int sw = ((((kk >> 3) + quad) ^ (lr & 7)) & 7) << 3;
        bf16x8 a0 = *(const bf16x8*)(&qs[(m0 + lr) * 64 + sw]);
        bf16x8 a1 = *(const bf16x8*)(&qs[(m0 + 16 + lr) * 64 + sw]);
#pragma unroll
        for (int i = 0; i < 8; ++i) {
            a0[i] = (__bf16)((float)a0[i] * qd0);
            a1[i] = (__bf16)((float)a1[i] * qd1);
        }
#pragma unroll
        for (int ni = 0; ni < 4; ++ni) {
            bf16x8 bk = *(const bf16x8*)(kvb + (ni * 16 + lr) * 64 + kk + quad * 8);
            oacc[0][ni] = __builtin_amdgcn_mfma_f32_16x16x32_bf16(a0, bk, oacc[0][ni], 0, 0, 0);
            oacc[1][ni] = __builtin_amdgcn_mfma_f32_16x16x32_bf16(a1, bk, oacc[1][ni], 0, 0, 0);
        }
    }
    __syncthreads();  // qs/kbs fully consumed; region reused for Ps/vT
    // factorized mask: exp(-s*(t-tp)) = exp(-s*(t-m0)) * exp(-s*max(m0-tp,-31))
    float ftv[2][4], gtv[8];
#pragma unroll
    for (int mi = 0; mi < 2; ++mi)
#pragma unroll
        for (int r = 0; r < 4; ++r) ftv[mi][r] = __expf(-slope * (float)(mi * 16 + quad * 4 + r));
#pragma unroll
    for (int ni = 0; ni < 8; ++ni)
        gtv[ni] = __expf(-slope * fmaxf((float)(m0 - (ni * 16 + lr)), -31.0f));
#pragma unroll
    for (int mi = 0; mi < 2; ++mi)
#pragma unroll
        for (int ni = 0; ni < 8; ++ni)
#pragma unroll
            for (int r = 0; r < 4; ++r) {
                int t = m0 + mi * 16 + quad * 4 + r;
                int tp = ni * 16 + lr;
                float val = (t >= tp) ? sacc[mi][ni][r] * ftv[mi][r] * gtv[ni] : 0.f;
                int sw = (((tp >> 3) & ~7) << 3) + ((((tp >> 3) ^ (t >> 3)) & 7) << 3) + (tp & 7);
                Ps[t * 136 + sw] = __float2bfloat16(val);
            }
    // stage v transposed (swizzled)
#pragma unroll
    for (int p = 0; p < 4; ++p) {
        int flat = p * 256 + tid;
        int t = flat >> 3, d0 = (flat & 7) * 8;
        size_t row = (size_t)(b * S_ + c * 128 + t);
        uint4 vw = *(const uint4*)(qkv + row * 1536 + 1280 + g * 64 + d0);
        const bf16* vp = (const bf16*)&vw;
#pragma unroll
        for (int i = 0; i < 8; ++i) {
            int e = d0 + i;
            int sw = (((t >> 3) & ~7) << 3) + ((((t >> 3) ^ (e >> 3)) & 7) << 3) + (t & 7);
            vT[e * 136 + sw] = vp[i];
        }
    }
    __syncthreads();
#pragma unroll
    for (int ks2 = 0; ks2 < 128; ks2 += 32) {
        int qa = (ks2 >> 3) + quad;             // chunk index 0..15
        int qhi = (qa & ~7) << 3;
        int ra0 = m0 + lr, ra1 = m0 + 16 + lr;
        bf16x8 af0 = *(const bf16x8*)(&Ps[ra0 * 136 + qhi + (((qa ^ (ra0 >> 3)) & 7) << 3)]);
        bf16x8 af1 = *(const bf16x8*)(&Ps[ra1 * 136 + qhi + (((qa ^ (ra1 >> 3)) & 7) << 3)]);
#pragma unroll
        for (int ni = 0; ni < 4; ++ni) {
            int eb = ni * 16 + lr;
            bf16x8 bfv = *(const bf16x8*)(&vT[eb * 136 + qhi + (((qa ^ (eb >> 3)) & 7) << 3)]);
            oacc[0][ni] = __builtin_amdgcn_mfma_f32_16x16x32_bf16(af0, bfv, oacc[0][ni], 0, 0, 0);
            oacc[1][ni] = __builtin_amdgcn_mfma_f32_16x16x32_bf16(af1, bfv, oacc[1][ni], 0, 0, 0);
        }
    }
#pragma unroll
    for (int mi = 0; mi < 2; ++mi)
#pragma unroll
        for (int ni = 0; ni < 4; ++ni)
#pragma unroll
            for (int r = 0; r < 4; ++r) {
                int t = m0 + mi * 16 + quad * 4 + r;
                int e = ni * 16 + lr;
                size_t row = (size_t)(b * S_ + c * 128 + t);
                outb[row * (NH_ * 64) + h * 64 + e] = __float2bfloat16(oacc[mi][ni][r]);
            }
}

extern "C" void kernel_launch(void* const* d_in, const int* in_sizes, int n_in,
                              void* d_out, int out_size, void* d_ws, size_t ws_size,
                              hipStream_t stream) {
    (void)in_sizes; (void)n_in; (void)out_size; (void)ws_size;
    const float* x  = (const float*)d_in[0];
    const float* Wq = (const float*)d_in[1];
    const float* Wk = (const float*)d_in[2];
    const float* Wv = (const float*)d_in[3];
    const float* Wo = (const float*)d_in[4];
    float* out = (float*)d_out;
    char* ws = (char*)d_ws;
    bf16*  xb    = (bf16*)(ws);                    // 33,554,432 (reused as attn_out)
    bf16*  qkvb  = (bf16*)(ws + 33554432);         // 50,331,648  [M][1536]: q|k|v
    bf16*  wqkvb = (bf16*)(ws + 83886080);         //  3,145,728  [1536][1024]
    bf16*  wob   = (bf16*)(ws + 87031808);         //  2,097,152
    float* cosd  = (float*)(ws + 89128960);        //  1,048,576
    float* sind  = (float*)(ws + 90177536);        //  1,048,576
    bf16*  Cbuf  = (bf16*)(ws + 91226112);         // 16,777,216
    bf16*  kvst  = (bf16*)(ws + 108003328);        // 16,777,216  -> total 124,780,544 B
    bf16*  attn  = xb;

    prep_kernel<<<19968, 256, 0, stream>>>(x, Wq, Wk, Wv, Wo, xb, wqkvb, wob, cosd, sind);

    // fused q|k|v projection with RoPE on cols < 1280 (q heads + k heads)
    gemm_bt_kernel<bf16><<<dim3(128, 12), 256, 0, stream>>>(xb, wqkvb, qkvb, 16384, 1536, 1024, 1280, cosd, sind);

    // per-GROUP chunk KV (4 heads/block, raw k/v staged once)
    chunk_kv_kernel<<<dim3(NC_, NKV_, B_), 512, 0, stream>>>(qkvb, Cbuf);
    scan_kv_kernel<<<512, 256, 0, stream>>>(Cbuf, kvst);
    attn_chunk_kernel<<<dim3(NC_, NH_, B_), 256, 0, stream>>>(qkvb, kvst, attn);

    gemm_bt_kernel<float><<<dim3(128, 8), 256, 0, stream>>>(attn, wob, out, 16384, 1024, 1024, 0, cosd, sind);
}